// Round 4
// baseline (206.072 us; speedup 1.0000x reference)
//
#include <hip/hip_runtime.h>

// Downsampling_77214922047594 — B=4, N=8192, M=32768, K=16, C=128, G=8, f32 I/O
// Round 4: RPB=32 (1024 blocks), W fragments register-resident (no W LDS tile),
// launch_bounds(256,4) -> 4 blocks/CU, idx staged in LDS, separate stats reduce.

constexpr int NPB = 8192;            // N per batch
constexpr int BN  = 32768;           // total rows
constexpr int CH  = 128;
constexpr int KNB = 16;              // neighbors
constexpr int MS  = 32768;           // s_feats rows per batch
constexpr int NG  = 8;               // groups
constexpr int CG  = 16;              // channels per group
constexpr int RPB = 32;              // rows per block
constexpr int NBLK = BN / RPB;       // 1024 blocks
constexpr int BPB  = NPB / RPB;      // 256 blocks per batch
constexpr int XS = 144;              // LDS stride (elements) for X tile

typedef short short8 __attribute__((ext_vector_type(8)));
typedef float floatx4 __attribute__((ext_vector_type(4)));

__device__ __forceinline__ unsigned short f2bs(float f) {
    unsigned int u = __builtin_bit_cast(unsigned int, f);
    unsigned int r = (u + 0x7fffu + ((u >> 16) & 1u)) >> 16;   // RNE
    return (unsigned short)r;
}
__device__ __forceinline__ float bs2f(unsigned short s) {
    unsigned int u = ((unsigned int)s) << 16;
    return __builtin_bit_cast(float, u);
}

// ------------- W transpose + bf16 cast: Wt[n][k] = W[k][n] -------------
// coalesced f32 reads, scattered 2B writes (writes don't stall).
__global__ __launch_bounds__(256) void k_prep(
    const float* __restrict__ W1, const float* __restrict__ W2,
    const float* __restrict__ W3,
    unsigned short* __restrict__ Wt1, unsigned short* __restrict__ Wt2,
    unsigned short* __restrict__ Wt3)
{
    const int bi = blockIdx.x;          // 0..191
    const int w  = bi >> 6;
    const int el = (bi & 63) * 256 + threadIdx.x;   // 0..16383
    const float* W = (w == 0) ? W1 : (w == 1) ? W2 : W3;
    unsigned short* Wt = (w == 0) ? Wt1 : (w == 1) ? Wt2 : Wt3;
    float v = W[el];
    int k = el >> 7, n = el & 127;
    Wt[n * 128 + k] = f2bs(v);
}

// ------------- stats reduce: partials (NBLK,16) -> (mean, rsqrt) -------------
__global__ __launch_bounds__(256) void k_reduce(
    const float* __restrict__ partials, float2* __restrict__ stats)
{
    const int bg = blockIdx.x;           // 0..31 = b*8+g
    const int b  = bg >> 3;
    const int g  = bg & 7;
    const int t  = threadIdx.x;          // one partial row each (256/batch)
    const float* p = partials + ((size_t)(b * BPB + t)) * 16;
    float s = p[g];
    float q = p[8 + g];
    __shared__ float ss[256], qq[256];
    ss[t] = s; qq[t] = q;
    __syncthreads();
    for (int off = 128; off; off >>= 1) {
        if (t < off) { ss[t] += ss[t + off]; qq[t] += qq[t + off]; }
        __syncthreads();
    }
    if (t == 0) {
        const float cnt  = (float)(NPB * CG);
        float mean = ss[0] / cnt;
        float var  = qq[0] / cnt - mean * mean;
        stats[bg] = make_float2(mean, rsqrtf(var + 1e-5f));
    }
}

// ------------- main pass kernel -------------
// MODE 0: IDW gather -> X;  MODE 1: GN(h_prev)+act -> X;  MODE 2: + resid qf
// then X(32x128) @ Wt^T via MFMA -> hout bf16 + per-block group partials.
template <int MODE>
__global__ __launch_bounds__(256, 4) void k_pass(
    const unsigned short* __restrict__ hin,   // bf16 pre-GN h (MODE 1,2)
    const float2* __restrict__ stats,         // (B*8)         (MODE 1,2)
    const float* __restrict__ gamma,          // prev layer GN (MODE 1,2)
    const float* __restrict__ beta,
    const float* __restrict__ qf,             // residual f32  (MODE 2)
    const float* __restrict__ sf,             // (B,M,C)       (MODE 0)
    const float* __restrict__ qp,             // (B,N,3)       (MODE 0)
    const float* __restrict__ sp,             // (B,N,K,3)     (MODE 0)
    const int*   __restrict__ idx,            // (B,N,K)       (MODE 0)
    const unsigned short* __restrict__ Wt,    // bf16 (n,k) 128x128
    const float* __restrict__ bias,           // this layer's bias
    unsigned short* __restrict__ hout,        // bf16 (BN,CH) pre-GN
    float* __restrict__ part_out)             // (NBLK,16)
{
    const int bi = blockIdx.x;
    const int t  = threadIdx.x;
    const int b  = bi >> 8;                   // bi / BPB

    const int w  = t >> 6;                    // wave 0..3 (owns n-tiles 2w,2w+1)
    const int l  = t & 63;
    const int lr = l & 15;
    const int qd = l >> 4;

    __shared__ unsigned short Xl[RPB * XS];   // 9216 B
    __shared__ float wv[RPB * KNB];           // 2048 B
    __shared__ int   ii[RPB * KNB];           // 2048 B
    __shared__ float winv[RPB];
    __shared__ float pw[4][4];

    // ---- preload this wave's W fragments + bias (in flight during phase 1) ----
    short8 wf[2][4];
    #pragma unroll
    for (int jj = 0; jj < 2; jj++)
        #pragma unroll
        for (int kt = 0; kt < 4; kt++)
            wf[jj][kt] = *(const short8*)(Wt + ((2 * w + jj) * 16 + lr) * 128
                                          + kt * 32 + qd * 8);
    float bjv[2] = {bias[(2 * w + 0) * 16 + lr], bias[(2 * w + 1) * 16 + lr]};

    if (MODE == 0) {
        // ---- IDW weights + idx staging: 512 (row,k) pairs ----
        #pragma unroll
        for (int i = 0; i < 2; i++) {
            int p = i * 256 + t;
            int row = p >> 4, k = p & 15;
            size_t rg = (size_t)bi * RPB + row;
            float qx = qp[rg * 3 + 0], qy = qp[rg * 3 + 1], qz = qp[rg * 3 + 2];
            const float* spp = sp + (rg * KNB + k) * 3;
            float dx = spp[0] - qx, dy = spp[1] - qy, dz = spp[2] - qz;
            wv[p] = 1.0f / (dx * dx + dy * dy + dz * dz + 1e-8f);
            ii[p] = idx[rg * KNB + k];
        }
        __syncthreads();
        if (t < RPB) {
            float s = 0.f;
            #pragma unroll
            for (int k = 0; k < KNB; k++) s += wv[t * KNB + k];
            winv[t] = 1.0f / s;
        }
        __syncthreads();
        // ---- gather: 8 groups x 32 lanes; 4 rows/group; float4 cols ----
        const int grp = t >> 5, c4 = (t & 31) * 4;
        #pragma unroll
        for (int rr = 0; rr < 4; rr++) {
            int row = grp * 4 + rr;
            float ax = 0.f, ay = 0.f, az = 0.f, aw = 0.f;
            #pragma unroll
            for (int k = 0; k < KNB; k++) {
                int j = ii[row * KNB + k];
                const float4 f = *(const float4*)(sf + ((size_t)b * MS + j) * CH + c4);
                float wk = wv[row * KNB + k];
                ax += wk * f.x; ay += wk * f.y; az += wk * f.z; aw += wk * f.w;
            }
            float wi = winv[row];
            ushort4 pk;
            pk.x = f2bs(ax * wi); pk.y = f2bs(ay * wi);
            pk.z = f2bs(az * wi); pk.w = f2bs(aw * wi);
            *(ushort4*)&Xl[row * XS + c4] = pk;
        }
    } else {
        // ---- GN + LeakyReLU (+resid) -> bf16 X tile; 16 elems/thread ----
        const int flat = t * 16;
        const int row = flat >> 7, col = flat & 127;     // col = 16-aligned
        size_t gidx = (size_t)bi * RPB * CH + flat;
        short8 h0 = *(const short8*)(hin + gidx);
        short8 h1 = *(const short8*)(hin + gidx + 8);
        float2 st = stats[b * NG + (col >> 4)];
        float gg[16], bb[16], re[16];
        #pragma unroll
        for (int e4 = 0; e4 < 4; e4++) {
            float4 g = *(const float4*)(gamma + col + e4 * 4);
            float4 bt = *(const float4*)(beta + col + e4 * 4);
            gg[e4*4+0]=g.x; gg[e4*4+1]=g.y; gg[e4*4+2]=g.z; gg[e4*4+3]=g.w;
            bb[e4*4+0]=bt.x; bb[e4*4+1]=bt.y; bb[e4*4+2]=bt.z; bb[e4*4+3]=bt.w;
            if (MODE == 2) {
                float4 r = *(const float4*)(qf + gidx + e4 * 4);
                re[e4*4+0]=r.x; re[e4*4+1]=r.y; re[e4*4+2]=r.z; re[e4*4+3]=r.w;
            }
        }
        unsigned short ov[16];
        #pragma unroll
        for (int e = 0; e < 16; e++) {
            unsigned short hs = (unsigned short)((e < 8) ? h0[e] : h1[e - 8]);
            float v = bs2f(hs);
            float y = (v - st.x) * st.y * gg[e] + bb[e];
            y = (y >= 0.f) ? y : 0.1f * y;
            if (MODE == 2) y += re[e];
            ov[e] = f2bs(y);
        }
        *(short8*)&Xl[row * XS + col]     = *(short8*)&ov[0];
        *(short8*)&Xl[row * XS + col + 8] = *(short8*)&ov[8];
    }
    __syncthreads();

    // ---- MFMA: 2 m-tiles x 2 n-tiles per wave, K = 4 x 32 ----
    floatx4 acc[2][2] = {};
    #pragma unroll
    for (int kt = 0; kt < 4; kt++) {
        short8 a0 = *(const short8*)&Xl[lr * XS + kt * 32 + qd * 8];
        short8 a1 = *(const short8*)&Xl[(16 + lr) * XS + kt * 32 + qd * 8];
        #pragma unroll
        for (int jj = 0; jj < 2; jj++) {
            acc[0][jj] = __builtin_amdgcn_mfma_f32_16x16x32_bf16(a0, wf[jj][kt], acc[0][jj], 0, 0, 0);
            acc[1][jj] = __builtin_amdgcn_mfma_f32_16x16x32_bf16(a1, wf[jj][kt], acc[1][jj], 0, 0, 0);
        }
    }

    // ---- epilogue: bias + group partials (group == n-tile j) ----
    #pragma unroll
    for (int jj = 0; jj < 2; jj++) {
        float ss = 0.f, qq = 0.f;
        #pragma unroll
        for (int m = 0; m < 2; m++)
            #pragma unroll
            for (int r = 0; r < 4; r++) {
                float v = acc[m][jj][r] + bjv[jj];
                ss += v; qq += v * v;
            }
        #pragma unroll
        for (int off = 32; off; off >>= 1) {
            ss += __shfl_down(ss, off);
            qq += __shfl_down(qq, off);
        }
        if (l == 0) { pw[w][jj] = ss; pw[w][2 + jj] = qq; }
    }
    __syncthreads();   // all MFMA reads of Xl done -> safe to overwrite
    // scatter C (bf16) into Xl: wave w owns cols [2w*16, 2w*16+32) — no overlap
    #pragma unroll
    for (int jj = 0; jj < 2; jj++)
        #pragma unroll
        for (int m = 0; m < 2; m++)
            #pragma unroll
            for (int r = 0; r < 4; r++)
                Xl[(m * 16 + qd * 4 + r) * XS + (2 * w + jj) * 16 + lr] =
                    f2bs(acc[m][jj][r] + bjv[jj]);
    __syncthreads();
    if (t < 16) {
        int g = t & 7, isq = t >> 3;
        part_out[(size_t)bi * 16 + t] = pw[g >> 1][(g & 1) + 2 * isq];
    }
    // linear copy Xl -> hout (coalesced short8)
    {
        const int flat = t * 16;
        const int row = flat >> 7, col = flat & 127;
        size_t gidx = (size_t)bi * RPB * CH + flat;
        *(short8*)(hout + gidx)     = *(const short8*)&Xl[row * XS + col];
        *(short8*)(hout + gidx + 8) = *(const short8*)&Xl[row * XS + col + 8];
    }
}

// ------------- final GN + LeakyReLU -> f32 out -------------
__global__ __launch_bounds__(256) void k_out(
    const unsigned short* __restrict__ hin, const float2* __restrict__ stats,
    const float* __restrict__ gamma, const float* __restrict__ beta,
    float* __restrict__ out)
{
    const int t = threadIdx.x;
    size_t fl = (size_t)blockIdx.x * 4096 + t * 16;
    const int b = (int)(fl >> 20);            // NPB*CH = 1<<20 per batch
    const int col = (int)(fl & 127);          // 16-aligned
    short8 h0 = *(const short8*)(hin + fl);
    short8 h1 = *(const short8*)(hin + fl + 8);
    float2 st = stats[b * NG + (col >> 4)];
    #pragma unroll
    for (int e4 = 0; e4 < 4; e4++) {
        float4 g = *(const float4*)(gamma + col + e4 * 4);
        float4 bt = *(const float4*)(beta + col + e4 * 4);
        float o[4];
        #pragma unroll
        for (int i = 0; i < 4; i++) {
            int e = e4 * 4 + i;
            unsigned short hs = (unsigned short)((e < 8) ? h0[e] : h1[e - 8]);
            float v = bs2f(hs);
            float gv = (i == 0) ? g.x : (i == 1) ? g.y : (i == 2) ? g.z : g.w;
            float bv = (i == 0) ? bt.x : (i == 1) ? bt.y : (i == 2) ? bt.z : bt.w;
            float y = (v - st.x) * st.y * gv + bv;
            o[i] = (y >= 0.f) ? y : 0.1f * y;
        }
        float4 ov = {o[0], o[1], o[2], o[3]};
        *(float4*)(out + fl + e4 * 4) = ov;
    }
}

extern "C" void kernel_launch(void* const* d_in, const int* in_sizes, int n_in,
                              void* d_out, int out_size, void* d_ws, size_t ws_size,
                              hipStream_t stream) {
    const float* qf  = (const float*)d_in[0];
    const float* sf  = (const float*)d_in[1];
    const float* qp  = (const float*)d_in[2];
    const float* sp  = (const float*)d_in[3];
    const int*   idx = (const int*)  d_in[4];
    const float* W1  = (const float*)d_in[5];
    const float* b1  = (const float*)d_in[6];
    const float* g1  = (const float*)d_in[7];
    const float* be1 = (const float*)d_in[8];
    const float* W2  = (const float*)d_in[9];
    const float* b2  = (const float*)d_in[10];
    const float* g2  = (const float*)d_in[11];
    const float* be2 = (const float*)d_in[12];
    const float* W3  = (const float*)d_in[13];
    const float* b3  = (const float*)d_in[14];
    const float* g3  = (const float*)d_in[15];
    const float* be3 = (const float*)d_in[16];

    char* ws = (char*)d_ws;
    unsigned short* Wt1 = (unsigned short*)(ws);
    unsigned short* Wt2 = (unsigned short*)(ws + 32768);
    unsigned short* Wt3 = (unsigned short*)(ws + 65536);
    float*  p1  = (float*)(ws + 98304);          // 1024*16*4 = 64 KB
    float*  p2  = (float*)(ws + 163840);
    float*  p3  = (float*)(ws + 229376);
    float2* st1 = (float2*)(ws + 294912);
    float2* st2 = (float2*)(ws + 295168);
    float2* st3 = (float2*)(ws + 295424);
    unsigned short* h1 = (unsigned short*)(ws + 327680);
    unsigned short* h2 = (unsigned short*)(ws + 327680 + 8388608);
    unsigned short* h3 = (unsigned short*)(ws + 327680 + 2 * 8388608);
    float* out = (float*)d_out;

    k_prep<<<192, 256, 0, stream>>>(W1, W2, W3, Wt1, Wt2, Wt3);
    k_pass<0><<<NBLK, 256, 0, stream>>>(nullptr, nullptr, nullptr, nullptr,
                                        nullptr, sf, qp, sp, idx,
                                        Wt1, b1, h1, p1);
    k_reduce<<<32, 256, 0, stream>>>(p1, st1);
    k_pass<1><<<NBLK, 256, 0, stream>>>(h1, st1, g1, be1, nullptr,
                                        nullptr, nullptr, nullptr, nullptr,
                                        Wt2, b2, h2, p2);
    k_reduce<<<32, 256, 0, stream>>>(p2, st2);
    k_pass<2><<<NBLK, 256, 0, stream>>>(h2, st2, g2, be2, qf,
                                        nullptr, nullptr, nullptr, nullptr,
                                        Wt3, b3, h3, p3);
    k_reduce<<<32, 256, 0, stream>>>(p3, st3);
    k_out<<<1024, 256, 0, stream>>>(h3, st3, g3, be3, out);
}